// Round 3
// baseline (64.643 us; speedup 1.0000x reference)
//
#include <hip/hip_runtime.h>

#define K_OBJ 64
#define NCOLR 10
#define HID 128
#define GH 2048
#define GWID 2048
#define NPIX (GH * GWID)
#define LN_EPS 1e-5f

// ws layout: ints [0,896) = hist[64][10], ymin[64], ymax[64], xmin[64], xmax[64]
// floats at byte 4096: kv[(l*2+m)][64][128]  (m=0: kp, m=1: vp), both layers

__global__ void init_kernel(int* __restrict__ acc) {
    int t = threadIdx.x;
    if (t < 640) acc[t] = 0;
    else if (t < 704) acc[t] = 0x7fffffff;      // ymin
    else if (t < 768) acc[t] = (int)0x80000000; // ymax
    else if (t < 832) acc[t] = 0x7fffffff;      // xmin
    else if (t < 896) acc[t] = (int)0x80000000; // xmax
}

#define RB_BLOCKS 1024
#define RB_TPB 256

__global__ __launch_bounds__(RB_TPB) void reduce_kernel(
        const int4* __restrict__ grid4, const int4* __restrict__ lab4,
        int* __restrict__ acc) {
    __shared__ int s_hist[K_OBJ * NCOLR];
    __shared__ int s_ymin[K_OBJ], s_ymax[K_OBJ], s_xmin[K_OBJ], s_xmax[K_OBJ];
    const int tid = threadIdx.x;
    for (int i = tid; i < K_OBJ * NCOLR; i += RB_TPB) s_hist[i] = 0;
    if (tid < K_OBJ) {
        s_ymin[tid] = 0x7fffffff; s_ymax[tid] = (int)0x80000000;
        s_xmin[tid] = 0x7fffffff; s_xmax[tid] = (int)0x80000000;
    }
    __syncthreads();

    const int lane = tid & 63;
    const int gw = blockIdx.x * (RB_TPB / 64) + (tid >> 6);
    const int ITER = NPIX / (RB_BLOCKS * RB_TPB * 4);  // = 4
    for (int it = 0; it < ITER; ++it) {
        const int ci = gw * ITER + it;
        const int base = ci * 256;              // chunk of 256 contiguous pixels
        const int4 g  = grid4[(base >> 2) + lane];
        const int4 lb = lab4[(base >> 2) + lane];
        const int row = base >> 11;             // GWID = 2048
        const int colbase = base & (GWID - 1);
        #pragma unroll
        for (int j = 0; j < 4; ++j) {
            const int lj = (j == 0) ? lb.x : (j == 1) ? lb.y : (j == 2) ? lb.z : lb.w;
            const int cj = (j == 0) ? g.x  : (j == 1) ? g.y  : (j == 2) ? g.z  : g.w;
            const bool pred = ((unsigned)lj < (unsigned)K_OBJ);
            const unsigned long long act = __ballot(pred);
            if (act == 0ull) continue;
            const int first = __builtin_ctzll(act);
            const int lab0 = __shfl(lj, first);
            const bool uni = __all((!pred) || (lj == lab0));
            if (uni) {
                if (lane == first) {
                    const int last = 63 - __builtin_clzll(act);
                    atomicMin(&s_xmin[lab0], colbase + first * 4 + j);
                    atomicMax(&s_xmax[lab0], colbase + last * 4 + j);
                    atomicMin(&s_ymin[lab0], row);
                    atomicMax(&s_ymax[lab0], row);
                }
                const int key = pred ? cj : -1;
                #pragma unroll
                for (int c = 0; c < NCOLR; ++c) {
                    const unsigned long long m = __ballot(key == c);
                    if (m && lane == first)
                        atomicAdd(&s_hist[lab0 * NCOLR + c], __popcll(m));
                }
            } else {
                if (pred) {
                    atomicAdd(&s_hist[lj * NCOLR + cj], 1);
                    const int xj = colbase + lane * 4 + j;
                    atomicMin(&s_xmin[lj], xj);
                    atomicMax(&s_xmax[lj], xj);
                    atomicMin(&s_ymin[lj], row);
                    atomicMax(&s_ymax[lj], row);
                }
            }
        }
    }
    __syncthreads();
    for (int i = tid; i < K_OBJ * NCOLR; i += RB_TPB) {
        const int v = s_hist[i];
        if (v) atomicAdd(&acc[i], v);
    }
    if (tid < K_OBJ) {
        if (s_ymin[tid] != 0x7fffffff)      atomicMin(&acc[640 + tid], s_ymin[tid]);
        if (s_ymax[tid] != (int)0x80000000) atomicMax(&acc[704 + tid], s_ymax[tid]);
        if (s_xmin[tid] != 0x7fffffff)      atomicMin(&acc[768 + tid], s_xmin[tid]);
        if (s_xmax[tid] != (int)0x80000000) atomicMax(&acc[832 + tid], s_xmax[tid]);
    }
}

// Fused: per-object features + K/V projections for both layers.
__global__ __launch_bounds__(HID) void feats_kv_kernel(
        const int* __restrict__ acc, const float* __restrict__ emb,
        const float* __restrict__ w1, const float* __restrict__ b1,
        const float* __restrict__ w2, const float* __restrict__ b2,
        const float* __restrict__ wqkv, const float* __restrict__ bqkv,
        float* __restrict__ kv) {
    const int k = blockIdx.x;   // object 0..63
    const int d = threadIdx.x;  // dim 0..127
    __shared__ float s_hid[HID];
    __shared__ float s_hist[NCOLR];
    __shared__ float s_geo[4];
    __shared__ float s_f[HID];
    if (d < NCOLR) s_hist[d] = (float)acc[k * NCOLR + d];
    if (d == 0) {
        int cnt = 0;
        for (int c = 0; c < NCOLR; ++c) cnt += acc[k * NCOLR + c];
        s_geo[0] = (float)(acc[704 + k] - acc[640 + k] + 1);
        s_geo[1] = (float)(acc[832 + k] - acc[768 + k] + 1);
        s_geo[2] = (float)cnt / (float)NPIX;
        s_geo[3] = (float)cnt;
    }
    __syncthreads();
    float hv = b1[d] + s_geo[0] * w1[d * 3 + 0] + s_geo[1] * w1[d * 3 + 1]
             + s_geo[2] * w1[d * 3 + 2];
    s_hid[d] = fmaxf(hv, 0.0f);
    __syncthreads();
    float geo = b2[d];
    #pragma unroll 8
    for (int j = 0; j < HID; ++j) geo += s_hid[j] * w2[d * HID + j];
    float ce = 0.0f;
    #pragma unroll
    for (int c = 0; c < NCOLR; ++c) ce += s_hist[c] * emb[c * HID + d];
    const float cnt = s_geo[3];
    ce = (cnt > 0.0f) ? (ce / cnt) : 0.0f;
    s_f[d] = 0.5f * (ce + geo);
    __syncthreads();
    // K/V projections: out (l, m, d) = feats[k] . W_row + bias
    #pragma unroll
    for (int lm = 0; lm < 4; ++lm) {
        const int l = lm >> 1, m = lm & 1;
        const float4* Wr = (const float4*)(wqkv + (size_t)l * 384 * HID
                                           + (size_t)(HID + m * HID + d) * HID);
        float s = bqkv[l * 384 + HID + m * HID + d];
        #pragma unroll 8
        for (int r = 0; r < 32; ++r) {
            const float4 w = Wr[r];
            const float* f = s_f + r * 4;
            s += w.x * f[0] + w.y * f[1] + w.z * f[2] + w.w * f[3];
        }
        kv[((size_t)(l * 2 + m) * K_OBJ + k) * HID + d] = s;
    }
}

#define TPB_ATTN 512

__global__ __launch_bounds__(TPB_ATTN) void attn_kernel(
        const float* __restrict__ kv, const float* __restrict__ query,
        const float* __restrict__ wqkv, const float* __restrict__ bqkv,
        const float* __restrict__ wo, const float* __restrict__ bo,
        const float* __restrict__ lnw, const float* __restrict__ lnb,
        float* __restrict__ out) {
    __shared__ float s_q[HID], s_qp[HID], s_attn[4][K_OBJ], s_oh[HID], s_r[HID];
    __shared__ float s_bq[2][HID], s_bo[2][HID], s_lnw[2][HID], s_lnb[2][HID];
    __shared__ float s_red[2], s_red2[2];
    const int tid = threadIdx.x;
    const int t4 = tid >> 2, p4 = tid & 3;   // 4 threads per 128-dot (t4 = out dim)
    const int t2 = tid >> 1, p2 = tid & 1;   // 2 threads per 32-dot (scores)
    const float scale = 0.17677669529663687f;  // 1/sqrt(32)

    // ---- Prefetch ALL serial-chain weights into registers (issued up front,
    // one memory latency total). 32 float4 = 128 VGPRs payload.
    const float4* pq0 = (const float4*)(wqkv + (size_t)t4 * HID + p4 * 32);
    const float4* pq1 = (const float4*)(wqkv + (size_t)384 * HID + (size_t)t4 * HID + p4 * 32);
    const float4* po0 = (const float4*)(wo + (size_t)t4 * HID + p4 * 32);
    const float4* po1 = (const float4*)(wo + (size_t)HID * HID + (size_t)t4 * HID + p4 * 32);
    float4 rq0[8], rq1[8], ro0[8], ro1[8];
    #pragma unroll
    for (int r = 0; r < 8; ++r) {
        rq0[r] = pq0[r]; rq1[r] = pq1[r]; ro0[r] = po0[r]; ro1[r] = po1[r];
    }
    if (tid < HID) {
        s_q[tid]     = query[tid];
        s_bq[0][tid] = bqkv[tid];       s_bq[1][tid] = bqkv[384 + tid];
        s_bo[0][tid] = bo[tid];         s_bo[1][tid] = bo[HID + tid];
        s_lnw[0][tid] = lnw[tid];       s_lnw[1][tid] = lnw[HID + tid];
        s_lnb[0][tid] = lnb[tid];       s_lnb[1][tid] = lnb[HID + tid];
    }
    __syncthreads();

    #pragma unroll
    for (int l = 0; l < 2; ++l) {
        const float4* RQ = (l == 0) ? rq0 : rq1;   // folds to regs after unroll
        const float4* RO = (l == 0) ? ro0 : ro1;
        const float* kp = kv + (size_t)(l * 2 + 0) * K_OBJ * HID;
        const float* vp = kv + (size_t)(l * 2 + 1) * K_OBJ * HID;

        // Phase A: qp[t4] = q . Wq[t4] + bq   (4 thr/out)
        {
            float a = 0.0f;
            const float* qv = s_q + p4 * 32;
            #pragma unroll
            for (int r = 0; r < 8; ++r) {
                const float4 w = RQ[r];
                a += w.x * qv[4*r] + w.y * qv[4*r+1] + w.z * qv[4*r+2] + w.w * qv[4*r+3];
            }
            a += __shfl_xor(a, 2, 4);
            a += __shfl_xor(a, 1, 4);
            if (p4 == 0) s_qp[t4] = a + s_bq[l][t4];
        }
        __syncthreads();
        // Phase B: scores[h][k] = scale * (qp_h . kp[k]_h)   (2 thr/out)
        {
            const int h = t2 >> 6, k = t2 & 63;
            const float4* kr = (const float4*)(kp + (size_t)k * HID + h * 32 + p2 * 16);
            const float* qh = s_qp + h * 32 + p2 * 16;
            float sc = 0.0f;
            #pragma unroll
            for (int r = 0; r < 4; ++r) {
                const float4 w = kr[r];
                sc += w.x * qh[4*r] + w.y * qh[4*r+1] + w.z * qh[4*r+2] + w.w * qh[4*r+3];
            }
            sc += __shfl_xor(sc, 1, 2);
            if (p2 == 0) s_attn[h][k] = sc * scale;
        }
        __syncthreads();
        // softmax per head (128 threads: 4 heads x 32 lanes)
        if (tid < 128) {
            const int h = tid >> 5, g = tid & 31;
            const float v0 = s_attn[h][g], v1 = s_attn[h][g + 32];
            float m = fmaxf(v0, v1);
            for (int off = 16; off >= 1; off >>= 1)
                m = fmaxf(m, __shfl_xor(m, off, 32));
            const float e0 = expf(v0 - m), e1 = expf(v1 - m);
            float s = e0 + e1;
            for (int off = 16; off >= 1; off >>= 1) s += __shfl_xor(s, off, 32);
            s_attn[h][g] = e0 / s;
            s_attn[h][g + 32] = e1 / s;
        }
        __syncthreads();
        // Phase D: oh[t4] = sum_k attn[h(t4)][k] * vp[k][t4]  (4 thr/out, 16 k each)
        // bv is inside vp; sum(attn)=1 carries it through exactly.
        {
            const int h = t4 >> 5;
            const float* vc = vp + t4;
            float a = 0.0f;
            #pragma unroll
            for (int i = 0; i < 16; ++i) {
                const int k = p4 * 16 + i;
                a += s_attn[h][k] * vc[(size_t)k * HID];
            }
            a += __shfl_xor(a, 2, 4);
            a += __shfl_xor(a, 1, 4);
            if (p4 == 0) s_oh[t4] = a;
        }
        __syncthreads();
        // Phase E: r[t4] = q[t4] + wo[t4] . oh + bo   (4 thr/out)
        {
            float a = 0.0f;
            const float* ov = s_oh + p4 * 32;
            #pragma unroll
            for (int r = 0; r < 8; ++r) {
                const float4 w = RO[r];
                a += w.x * ov[4*r] + w.y * ov[4*r+1] + w.z * ov[4*r+2] + w.w * ov[4*r+3];
            }
            a += __shfl_xor(a, 2, 4);
            a += __shfl_xor(a, 1, 4);
            if (p4 == 0) s_r[t4] = s_q[t4] + a + s_bo[l][t4];
        }
        __syncthreads();
        // LayerNorm (first 128 threads)
        float r_ln = 0.0f, dv = 0.0f;
        if (tid < 128) {
            r_ln = s_r[tid];
            float v = r_ln;
            for (int off = 32; off >= 1; off >>= 1) v += __shfl_xor(v, off, 64);
            if ((tid & 63) == 0) s_red[tid >> 6] = v;
        }
        __syncthreads();
        if (tid < 128) {
            const float mu = (s_red[0] + s_red[1]) * (1.0f / HID);
            dv = r_ln - mu;
            float v2 = dv * dv;
            for (int off = 32; off >= 1; off >>= 1) v2 += __shfl_xor(v2, off, 64);
            if ((tid & 63) == 0) s_red2[tid >> 6] = v2;
        }
        __syncthreads();
        if (tid < 128) {
            const float var = (s_red2[0] + s_red2[1]) * (1.0f / HID);
            s_q[tid] = dv * rsqrtf(var + LN_EPS) * s_lnw[l][tid] + s_lnb[l][tid];
        }
        __syncthreads();
    }
    if (tid < HID) out[tid] = s_q[tid];
}

extern "C" void kernel_launch(void* const* d_in, const int* in_sizes, int n_in,
                              void* d_out, int out_size, void* d_ws, size_t ws_size,
                              hipStream_t stream) {
    const int4* grid4 = (const int4*)d_in[0];
    const int4* lab4  = (const int4*)d_in[1];
    const float* emb  = (const float*)d_in[2];
    const float* gw1  = (const float*)d_in[3];
    const float* gb1  = (const float*)d_in[4];
    const float* gw2  = (const float*)d_in[5];
    const float* gb2  = (const float*)d_in[6];
    const float* query = (const float*)d_in[7];
    const float* wqkv = (const float*)d_in[8];
    const float* bqkv = (const float*)d_in[9];
    const float* wo   = (const float*)d_in[10];
    const float* bo   = (const float*)d_in[11];
    const float* lnw  = (const float*)d_in[12];
    const float* lnb  = (const float*)d_in[13];

    int* acc = (int*)d_ws;
    float* kvbuf = (float*)((char*)d_ws + 4096);

    hipLaunchKernelGGL(init_kernel, dim3(1), dim3(1024), 0, stream, acc);
    hipLaunchKernelGGL(reduce_kernel, dim3(RB_BLOCKS), dim3(RB_TPB), 0, stream,
                       grid4, lab4, acc);
    hipLaunchKernelGGL(feats_kv_kernel, dim3(K_OBJ), dim3(HID), 0, stream,
                       acc, emb, gw1, gb1, gw2, gb2, wqkv, bqkv, kvbuf);
    hipLaunchKernelGGL(attn_kernel, dim3(1), dim3(TPB_ATTN), 0, stream,
                       kvbuf, query, wqkv, bqkv, wo, bo, lnw, lnb, (float*)d_out);
}

// Round 4
// 57.733 us; speedup vs baseline: 1.1197x; 1.1197x over previous
//
#include <hip/hip_runtime.h>
#include <limits.h>

#define K_OBJ 64
#define NCOLR 10
#define HID 128
#define GH 2048
#define GWID 2048
#define NPIX (GH * GWID)
#define LN_EPS 1e-5f

#define RB_BLOCKS 1024
#define RB_TPB 256
#define NSTAT 896   // hist[64][10] | ymin[64] | ymax[64] | xmin[64] | xmax[64]

// ws layout:
//   bytes [0, 896*1024*4)            : partials, transposed part[stat][block]
//   bytes [4<<20, (4<<20)+128KB)     : kv[(l*2+m)][64][128] floats (m=0 kp, m=1 vp)

__global__ __launch_bounds__(RB_TPB) void reduce_kernel(
        const int4* __restrict__ grid4, const int4* __restrict__ lab4,
        int* __restrict__ part) {
    __shared__ int s_hist[K_OBJ * NCOLR];
    __shared__ int s_ymin[K_OBJ], s_ymax[K_OBJ], s_xmin[K_OBJ], s_xmax[K_OBJ];
    const int tid = threadIdx.x;
    for (int i = tid; i < K_OBJ * NCOLR; i += RB_TPB) s_hist[i] = 0;
    if (tid < K_OBJ) {
        s_ymin[tid] = INT_MAX; s_ymax[tid] = INT_MIN;
        s_xmin[tid] = INT_MAX; s_xmax[tid] = INT_MIN;
    }
    __syncthreads();

    const int lane = tid & 63;
    const int gw = blockIdx.x * (RB_TPB / 64) + (tid >> 6);
    const int ITER = NPIX / (RB_BLOCKS * RB_TPB * 4);  // = 16 chunks per wave
    for (int it = 0; it < ITER; ++it) {
        const int ci = gw * ITER + it;
        const int base = ci * 256;              // 256 contiguous pixels, one row slice
        const int4 g  = grid4[(base >> 2) + lane];
        const int4 lb = lab4[(base >> 2) + lane];
        const int row = base >> 11;             // GWID = 2048
        const int colbase = base & (GWID - 1);
        #pragma unroll
        for (int j = 0; j < 4; ++j) {
            const int lj = (j == 0) ? lb.x : (j == 1) ? lb.y : (j == 2) ? lb.z : lb.w;
            const int cj = (j == 0) ? g.x  : (j == 1) ? g.y  : (j == 2) ? g.z  : g.w;
            const bool pred = ((unsigned)lj < (unsigned)K_OBJ);
            const unsigned long long act = __ballot(pred);
            if (act == 0ull) continue;
            const int first = __builtin_ctzll(act);
            const int lab0 = __shfl(lj, first);
            const bool uni = __all((!pred) || (lj == lab0));
            if (uni) {  // whole chunk within one label block: wave-cooperative path
                if (lane == first) {
                    const int last = 63 - __builtin_clzll(act);
                    atomicMin(&s_xmin[lab0], colbase + first * 4 + j);
                    atomicMax(&s_xmax[lab0], colbase + last * 4 + j);
                    atomicMin(&s_ymin[lab0], row);
                    atomicMax(&s_ymax[lab0], row);
                }
                const int key = pred ? cj : -1;
                #pragma unroll
                for (int c = 0; c < NCOLR; ++c) {
                    const unsigned long long m = __ballot(key == c);
                    if (m && lane == first)
                        atomicAdd(&s_hist[lab0 * NCOLR + c], __popcll(m));
                }
            } else {
                if (pred) {
                    atomicAdd(&s_hist[lj * NCOLR + cj], 1);
                    const int xj = colbase + lane * 4 + j;
                    atomicMin(&s_xmin[lj], xj);
                    atomicMax(&s_xmax[lj], xj);
                    atomicMin(&s_ymin[lj], row);
                    atomicMax(&s_ymax[lj], row);
                }
            }
        }
    }
    __syncthreads();
    // non-atomic partial flush, transposed: part[stat][block]
    for (int i = tid; i < NSTAT; i += RB_TPB) {
        int v;
        if (i < 640)      v = s_hist[i];
        else if (i < 704) v = s_ymin[i - 640];
        else if (i < 768) v = s_ymax[i - 704];
        else if (i < 832) v = s_xmin[i - 768];
        else              v = s_xmax[i - 832];
        part[i * RB_BLOCKS + blockIdx.x] = v;
    }
}

// Merge partials + per-object features + K/V projections (both layers).
__global__ __launch_bounds__(256) void feats_kv_kernel(
        const int* __restrict__ part, const float* __restrict__ emb,
        const float* __restrict__ w1, const float* __restrict__ b1,
        const float* __restrict__ w2, const float* __restrict__ b2,
        const float* __restrict__ wqkv, const float* __restrict__ bqkv,
        float* __restrict__ kv) {
    const int k = blockIdx.x;   // object 0..63
    const int tid = threadIdx.x;
    __shared__ int s_h[NCOLR], s_ymn, s_ymx, s_xmn, s_xmx;
    __shared__ float s_hid[HID], s_f[HID];
    if (tid < NCOLR) s_h[tid] = 0;
    if (tid == 0) { s_ymn = INT_MAX; s_xmn = INT_MAX; }
    if (tid == 1) { s_ymx = INT_MIN; s_xmx = INT_MIN; }
    __syncthreads();
    {
        int h[NCOLR];
        #pragma unroll
        for (int c = 0; c < NCOLR; ++c) h[c] = 0;
        int ymn = INT_MAX, ymx = INT_MIN, xmn = INT_MAX, xmx = INT_MIN;
        #pragma unroll
        for (int b4 = 0; b4 < RB_BLOCKS / 256; ++b4) {
            const int b = b4 * 256 + tid;
            #pragma unroll
            for (int c = 0; c < NCOLR; ++c)
                h[c] += part[(k * NCOLR + c) * RB_BLOCKS + b];
            ymn = min(ymn, part[(640 + k) * RB_BLOCKS + b]);
            ymx = max(ymx, part[(704 + k) * RB_BLOCKS + b]);
            xmn = min(xmn, part[(768 + k) * RB_BLOCKS + b]);
            xmx = max(xmx, part[(832 + k) * RB_BLOCKS + b]);
        }
        #pragma unroll
        for (int off = 32; off >= 1; off >>= 1) {
            #pragma unroll
            for (int c = 0; c < NCOLR; ++c) h[c] += __shfl_xor(h[c], off, 64);
            ymn = min(ymn, __shfl_xor(ymn, off, 64));
            ymx = max(ymx, __shfl_xor(ymx, off, 64));
            xmn = min(xmn, __shfl_xor(xmn, off, 64));
            xmx = max(xmx, __shfl_xor(xmx, off, 64));
        }
        if ((tid & 63) == 0) {
            #pragma unroll
            for (int c = 0; c < NCOLR; ++c) atomicAdd(&s_h[c], h[c]);
            atomicMin(&s_ymn, ymn); atomicMax(&s_ymx, ymx);
            atomicMin(&s_xmn, xmn); atomicMax(&s_xmx, xmx);
        }
    }
    __syncthreads();
    // features (threads 0..127)
    const int d = tid & 127;
    float cntf;
    {
        int cnt = 0;
        #pragma unroll
        for (int c = 0; c < NCOLR; ++c) cnt += s_h[c];
        cntf = (float)cnt;
    }
    if (tid < HID) {
        const float gh = (float)(s_ymx - s_ymn + 1);
        const float gw = (float)(s_xmx - s_xmn + 1);
        const float af = cntf / (float)NPIX;
        float hv = b1[d] + gh * w1[d * 3 + 0] + gw * w1[d * 3 + 1] + af * w1[d * 3 + 2];
        s_hid[d] = fmaxf(hv, 0.0f);
    }
    __syncthreads();
    if (tid < HID) {
        float geo = b2[d];
        #pragma unroll 8
        for (int j = 0; j < HID; ++j) geo += s_hid[j] * w2[d * HID + j];
        float ce = 0.0f;
        #pragma unroll
        for (int c = 0; c < NCOLR; ++c) ce += (float)s_h[c] * emb[c * HID + d];
        ce = (cntf > 0.0f) ? (ce / cntf) : 0.0f;
        s_f[d] = 0.5f * (ce + geo);
    }
    __syncthreads();
    // K/V projections: tid -> (m = tid>>7, d); loop layers
    const int m = tid >> 7;
    #pragma unroll
    for (int l = 0; l < 2; ++l) {
        const float4* Wr = (const float4*)(wqkv + (size_t)l * 384 * HID
                                           + (size_t)(HID + m * HID + d) * HID);
        float s = bqkv[l * 384 + HID + m * HID + d];
        #pragma unroll 8
        for (int r = 0; r < 32; ++r) {
            const float4 w = Wr[r];
            const float* f = s_f + r * 4;
            s += w.x * f[0] + w.y * f[1] + w.z * f[2] + w.w * f[3];
        }
        kv[((size_t)(l * 2 + m) * K_OBJ + k) * HID + d] = s;
    }
}

#define TPB_ATTN 1024

__global__ __launch_bounds__(TPB_ATTN) void attn_kernel(
        const float* __restrict__ kv, const float* __restrict__ query,
        const float* __restrict__ wqkv, const float* __restrict__ bqkv,
        const float* __restrict__ wo, const float* __restrict__ bo,
        const float* __restrict__ lnw, const float* __restrict__ lnb,
        float* __restrict__ out) {
    __shared__ float s_q[HID], s_qp[HID], s_attn[4][K_OBJ], s_oh[HID], s_r[HID];
    __shared__ float s_red[2], s_red2[2];
    const int tid = threadIdx.x;
    const int t8 = tid >> 3, p8 = tid & 7;   // 8 threads per 128-dot
    const int p4 = tid & 3;                  // 4 threads per 32-dot (scores)
    const float scale = 0.17677669529663687f;  // 1/sqrt(32)

    if (tid < HID) s_q[tid] = query[tid];
    __syncthreads();

    #pragma unroll
    for (int l = 0; l < 2; ++l) {
        const float* Wq = wqkv + (size_t)l * 384 * HID;
        const float* kp = kv + (size_t)(l * 2 + 0) * K_OBJ * HID;
        const float* vp = kv + (size_t)(l * 2 + 1) * K_OBJ * HID;

        // Phase A: qp[t8] = q . Wq[t8] + bq[t8]   (8 thr/out, direct loads)
        {
            const float4* Wr = (const float4*)(Wq + (size_t)t8 * HID + p8 * 16);
            const float* qv = s_q + p8 * 16;
            float a = 0.0f;
            #pragma unroll
            for (int r = 0; r < 4; ++r) {
                const float4 w = Wr[r];
                a += w.x * qv[4*r] + w.y * qv[4*r+1] + w.z * qv[4*r+2] + w.w * qv[4*r+3];
            }
            a += __shfl_xor(a, 4, 8);
            a += __shfl_xor(a, 2, 8);
            a += __shfl_xor(a, 1, 8);
            if (p8 == 0) s_qp[t8] = a + bqkv[l * 384 + t8];
        }
        __syncthreads();
        // Phase B: scores[h][k] = scale * (qp_h . kp[k]_h)  (4 thr/out; bk inside kp)
        {
            const int o = tid >> 2, h = o >> 6, k = o & 63;
            const float4* kr = (const float4*)(kp + (size_t)k * HID + h * 32 + p4 * 8);
            const float* qh = s_qp + h * 32 + p4 * 8;
            float sc = 0.0f;
            #pragma unroll
            for (int r = 0; r < 2; ++r) {
                const float4 w = kr[r];
                sc += w.x * qh[4*r] + w.y * qh[4*r+1] + w.z * qh[4*r+2] + w.w * qh[4*r+3];
            }
            sc += __shfl_xor(sc, 2, 4);
            sc += __shfl_xor(sc, 1, 4);
            if (p4 == 0) s_attn[h][k] = sc * scale;
        }
        __syncthreads();
        // softmax per head (128 threads: 4 heads x 32 lanes)
        if (tid < 128) {
            const int h = tid >> 5, g = tid & 31;
            const float v0 = s_attn[h][g], v1 = s_attn[h][g + 32];
            float m = fmaxf(v0, v1);
            for (int off = 16; off >= 1; off >>= 1)
                m = fmaxf(m, __shfl_xor(m, off, 32));
            const float e0 = expf(v0 - m), e1 = expf(v1 - m);
            float s = e0 + e1;
            for (int off = 16; off >= 1; off >>= 1) s += __shfl_xor(s, off, 32);
            s_attn[h][g] = e0 / s;
            s_attn[h][g + 32] = e1 / s;
        }
        __syncthreads();
        // Phase D: oh[t8] = sum_k attn[h][k] * vp[k][t8]  (8 thr/out, 8 k each;
        // bv inside vp, sum(attn)=1 carries it exactly)
        {
            const int h = t8 >> 5;
            const float* vc = vp + t8;
            float a = 0.0f;
            #pragma unroll
            for (int i = 0; i < 8; ++i) {
                const int k = p8 * 8 + i;
                a += s_attn[h][k] * vc[(size_t)k * HID];
            }
            a += __shfl_xor(a, 4, 8);
            a += __shfl_xor(a, 2, 8);
            a += __shfl_xor(a, 1, 8);
            if (p8 == 0) s_oh[t8] = a;
        }
        __syncthreads();
        // Phase E: r[t8] = q[t8] + wo[t8] . oh + bo[t8]  (8 thr/out, direct loads)
        {
            const float4* Wr = (const float4*)(wo + (size_t)l * HID * HID
                                               + (size_t)t8 * HID + p8 * 16);
            const float* ov = s_oh + p8 * 16;
            float a = 0.0f;
            #pragma unroll
            for (int r = 0; r < 4; ++r) {
                const float4 w = Wr[r];
                a += w.x * ov[4*r] + w.y * ov[4*r+1] + w.z * ov[4*r+2] + w.w * ov[4*r+3];
            }
            a += __shfl_xor(a, 4, 8);
            a += __shfl_xor(a, 2, 8);
            a += __shfl_xor(a, 1, 8);
            if (p8 == 0) s_r[t8] = s_q[t8] + a + bo[l * HID + t8];
        }
        __syncthreads();
        // LayerNorm (first 128 threads)
        float r_ln = 0.0f, dv = 0.0f;
        if (tid < 128) {
            r_ln = s_r[tid];
            float v = r_ln;
            for (int off = 32; off >= 1; off >>= 1) v += __shfl_xor(v, off, 64);
            if ((tid & 63) == 0) s_red[tid >> 6] = v;
        }
        __syncthreads();
        if (tid < 128) {
            const float mu = (s_red[0] + s_red[1]) * (1.0f / HID);
            dv = r_ln - mu;
            float v2 = dv * dv;
            for (int off = 32; off >= 1; off >>= 1) v2 += __shfl_xor(v2, off, 64);
            if ((tid & 63) == 0) s_red2[tid >> 6] = v2;
        }
        __syncthreads();
        if (tid < 128) {
            const float var = (s_red2[0] + s_red2[1]) * (1.0f / HID);
            s_q[tid] = dv * rsqrtf(var + LN_EPS) * lnw[l * HID + tid]
                     + lnb[l * HID + tid];
        }
        __syncthreads();
    }
    if (tid < HID) out[tid] = s_q[tid];
}

extern "C" void kernel_launch(void* const* d_in, const int* in_sizes, int n_in,
                              void* d_out, int out_size, void* d_ws, size_t ws_size,
                              hipStream_t stream) {
    const int4* grid4 = (const int4*)d_in[0];
    const int4* lab4  = (const int4*)d_in[1];
    const float* emb  = (const float*)d_in[2];
    const float* gw1  = (const float*)d_in[3];
    const float* gb1  = (const float*)d_in[4];
    const float* gw2  = (const float*)d_in[5];
    const float* gb2  = (const float*)d_in[6];
    const float* query = (const float*)d_in[7];
    const float* wqkv = (const float*)d_in[8];
    const float* bqkv = (const float*)d_in[9];
    const float* wo   = (const float*)d_in[10];
    const float* bo   = (const float*)d_in[11];
    const float* lnw  = (const float*)d_in[12];
    const float* lnb  = (const float*)d_in[13];

    int* part = (int*)d_ws;
    float* kvbuf = (float*)((char*)d_ws + (4 << 20));

    hipLaunchKernelGGL(reduce_kernel, dim3(RB_BLOCKS), dim3(RB_TPB), 0, stream,
                       grid4, lab4, part);
    hipLaunchKernelGGL(feats_kv_kernel, dim3(K_OBJ), dim3(256), 0, stream,
                       part, emb, gw1, gb1, gw2, gb2, wqkv, bqkv, kvbuf);
    hipLaunchKernelGGL(attn_kernel, dim3(1), dim3(TPB_ATTN), 0, stream,
                       kvbuf, query, wqkv, bqkv, wo, bo, lnw, lnb, (float*)d_out);
}